// Round 6
// baseline (175.748 us; speedup 1.0000x reference)
//
#include <hip/hip_runtime.h>
#include <float.h>
#include <math.h>

#define NB 128
#define NQ 16
#define ND 800
#define NE 300

// workspace layout (float offsets). All regions written every call.
#define WS_SIM    0                          // [NB][NQ][ND] raw dots (= cosine, unit rows)
#define WS_CTXINV (NB*NQ*ND)                 // [NB][ND] 1/(||ctx||/9+1e-9)
#define WS_SCORES (WS_CTXINV + NB*ND)        // [NB][NQ][13] (slots 6..12 used)
#define WS_C2     (WS_SCORES + NB*NQ*13)     // [NB][NQ][3][4 strips][2] partial top2
#define WS_QBF    (WS_C2 + NB*NQ*24)         // [NB][16][320] bf16 (q, zero-padded K)

#define PITCH 344                             // LDS row pitch in bf16 elems (688 B)

typedef __attribute__((ext_vector_type(8))) short short8;
typedef __attribute__((ext_vector_type(4))) float f32x4;

__device__ __forceinline__ unsigned short f2bf(float x) {   // RNE fp32->bf16
    unsigned u = __float_as_uint(x);
    u += 0x7FFF + ((u >> 16) & 1);
    return (unsigned short)(u >> 16);
}

__device__ __forceinline__ float bf2f(unsigned short u) {
    return __uint_as_float(((unsigned)u) << 16);
}

__device__ __forceinline__ void ins6(float t[6], float v) {
    if (v > t[5]) t[5] = v;
    float a;
    if (t[5] > t[4]) { a = t[4]; t[4] = t[5]; t[5] = a; }
    if (t[4] > t[3]) { a = t[3]; t[3] = t[4]; t[4] = a; }
    if (t[3] > t[2]) { a = t[2]; t[2] = t[3]; t[3] = a; }
    if (t[2] > t[1]) { a = t[1]; t[1] = t[2]; t[2] = a; }
    if (t[1] > t[0]) { a = t[0]; t[0] = t[1]; t[1] = a; }
}

__device__ __forceinline__ void ins2(float& a1, float& a2, float v) {
    if (v > a2) a2 = v;
    if (a2 > a1) { float t = a1; a1 = a2; a2 = t; }
}

__device__ __forceinline__ void merge2(float& a1, float& a2, float b1v, float b2v) {
    float hi = fmaxf(a1, b1v), lo = fminf(a1, b1v);
    a1 = hi;
    a2 = fmaxf(lo, fmaxf(a2, b2v));
}

// sliding sum of 8 consecutive lanes (this lane .. lane+7)
__device__ __forceinline__ float slide8(float s) {
    s += __shfl_down(s, 1);
    s += __shfl_down(s, 2);
    s += __shfl_down(s, 4);
    return s;
}

// ------- kq: q -> bf16 [16][320] (zero-padded) + idf -------
__global__ __launch_bounds__(256) void kq(const int* __restrict__ qrls,
                                          const float* __restrict__ emb,
                                          const float* __restrict__ idf,
                                          float* __restrict__ ws) {
    int b = blockIdx.x;
    int tid = threadIdx.x;
    unsigned short* qbf = (unsigned short*)(ws + WS_QBF) + (size_t)b * 16 * 320;
    for (int idx = tid; idx < 16 * 160; idx += 256) {
        int q = idx / 160, pr = idx % 160;
        int row = qrls[b * NQ + q];
        int e = pr * 2;
        float x0 = (e < NE) ? emb[(size_t)row * NE + e] : 0.f;
        float x1 = (e + 1 < NE) ? emb[(size_t)row * NE + e + 1] : 0.f;
        unsigned pack = (unsigned)f2bf(x0) | ((unsigned)f2bf(x1) << 16);
        *(unsigned*)(qbf + q * 320 + e) = pack;
    }
    if (tid < NQ) {
        int row = qrls[b * NQ + tid];
        ws[WS_SCORES + (b * NQ + tid) * 13 + 12] = idf[row];
    }
}

// ------- kfused: grid (13, NB), 256 thr = 4 waves -------
// Single doc-row gather per 64-col block: stage 72 rows (4-row halo) as bf16
// into LDS via coalesced per-row streams, then:
//   - MFMA sim: wave wv computes 16q x 16d tile (B-frags from LDS, 2-way-bank free)
//   - ctx-norm: waves 0,1 slide8 over staged rows (no second gather)
__global__ __launch_bounds__(256) void kfused(const int* __restrict__ docw,
                                              const float* __restrict__ emb,
                                              float* __restrict__ ws) {
    int b = blockIdx.y;
    int base = blockIdx.x * 64;
    int tid = threadIdx.x;
    __shared__ unsigned short slds[72 * PITCH];   // 49.5 KB

    // ---- stage: 72 rows x 40 segs (8 bf16 each); segs 38,39 zero K-pad ----
    for (int idx = tid; idx < 72 * 40; idx += 256) {
        int r = idx / 40, seg = idx - r * 40;
        int rg = base - 4 + r;
        short8 v = {0, 0, 0, 0, 0, 0, 0, 0};
        if (seg < 38 && rg >= 0 && rg < ND) {
            int row = docw[b * ND + rg];
            const float* p = emb + (size_t)row * NE + seg * 8;
            float4 a = *(const float4*)p;
            float4 c = {0.f, 0.f, 0.f, 0.f};
            if (seg < 37) c = *(const float4*)(p + 4);
            v[0] = (short)f2bf(a.x); v[1] = (short)f2bf(a.y);
            v[2] = (short)f2bf(a.z); v[3] = (short)f2bf(a.w);
            v[4] = (short)f2bf(c.x); v[5] = (short)f2bf(c.y);
            v[6] = (short)f2bf(c.z); v[7] = (short)f2bf(c.w);
        }
        *(short8*)&slds[r * PITCH + seg * 8] = v;
    }
    __syncthreads();

    int wv = tid >> 6, lane = tid & 63;
    int rsub = lane & 15, kgrp = lane >> 4;

    // ---- MFMA sim tile: cols base+16*wv .. +16, all 16 q, K=320 ----
    const unsigned short* qb = (const unsigned short*)(ws + WS_QBF)
                               + ((size_t)b * 16 + rsub) * 320 + kgrp * 8;
    short8 afr[10];
#pragma unroll
    for (int k = 0; k < 10; ++k)
        afr[k] = *(const short8*)(qb + k * 32);

    f32x4 acc = {0.f, 0.f, 0.f, 0.f};
    const unsigned short* bp = &slds[(16 * wv + rsub + 4) * PITCH + kgrp * 8];
#pragma unroll
    for (int k = 0; k < 10; ++k) {
        short8 bf = *(const short8*)(bp + k * 32);
        acc = __builtin_amdgcn_mfma_f32_16x16x32_bf16(afr[k], bf, acc, 0, 0, 0);
    }
    int col = base + 16 * wv + rsub;
    if (col < ND) {
        float* simp = ws + WS_SIM + (size_t)b * NQ * ND + col;
#pragma unroll
        for (int i = 0; i < 4; ++i)
            simp[(size_t)(kgrp * 4 + i) * ND] = acc[i];
    }

    // ---- ctx-norm: waves 0,1; lane l holds staged row 32*wv + l (l<40) ----
    if (wv < 2) {
        int rl = 32 * wv + lane;
        float sq = 0.f;
        for (int seg = 0; seg < 38; ++seg) {
            float xs[8];
            if (lane < 40) {
                short8 x = *(const short8*)&slds[rl * PITCH + seg * 8];
#pragma unroll
                for (int e = 0; e < 8; ++e) xs[e] = bf2f((unsigned short)x[e]);
            } else {
#pragma unroll
                for (int e = 0; e < 8; ++e) xs[e] = 0.f;
            }
#pragma unroll
            for (int e = 0; e < 8; ++e) {
                float s = slide8(xs[e]);
                sq = fmaf(s, s, sq);
            }
        }
        int d = base + 32 * wv + lane;
        if (lane < 32 && d < ND)
            ws[WS_CTXINV + b * ND + d] = 1.f / (sqrtf(sq) * (1.f / 9.f) + 1e-9f);
    }
}

// ------- kctxtop: prefix scan of raw dots -> context cosine -> top-6 -------
__global__ __launch_bounds__(256) void kctxtop(float* __restrict__ ws) {
    int b = blockIdx.y;
    int w = threadIdx.x >> 6, lane = threadIdx.x & 63;
    int q = blockIdx.x * 4 + w;
    __shared__ float P[4][ND];
    const float* simrow = ws + WS_SIM + (size_t)(b * NQ + q) * ND;
    const float* cinv = ws + WS_CTXINV + b * ND;
    float carry = 0.f;
    for (int c = 0; c < 13; ++c) {
        int d = c * 64 + lane;
        float v = (d < ND) ? simrow[d] : 0.f;
#pragma unroll
        for (int off = 1; off < 64; off <<= 1) {
            float t = __shfl_up(v, off);
            if (lane >= off) v += t;
        }
        v += carry;
        if (d < ND) P[w][d] = v;
        carry = __shfl(v, 63);
    }
    __syncthreads();
    float top[6] = {-FLT_MAX,-FLT_MAX,-FLT_MAX,-FLT_MAX,-FLT_MAX,-FLT_MAX};
    for (int c = 0; c < 13; ++c) {
        int d = c * 64 + lane;
        if (d < ND) {
            int hi_i = (d + 3 < ND) ? d + 3 : ND - 1;
            float hi = P[w][hi_i];
            float lo = (d >= 5) ? P[w][d - 5] : 0.f;
            float ctx = (hi - lo) * (1.f / 9.f) * cinv[d];
            ins6(top, ctx);
        }
    }
#pragma unroll
    for (int m = 1; m < 64; m <<= 1) {
        float o0 = __shfl_xor(top[0], m), o1 = __shfl_xor(top[1], m);
        float o2 = __shfl_xor(top[2], m), o3 = __shfl_xor(top[3], m);
        float o4 = __shfl_xor(top[4], m), o5 = __shfl_xor(top[5], m);
        ins6(top, o0); ins6(top, o1); ins6(top, o2);
        ins6(top, o3); ins6(top, o4); ins6(top, o5);
    }
    if (lane == 0) {
        float* sc = ws + WS_SCORES + (size_t)(b * NQ + q) * 13;
        sc[6] = top[0]; sc[7] = top[1]; sc[8]  = top[2];
        sc[9] = top[3]; sc[10] = top[4]; sc[11] = top[5];
    }
}

// ------- kconv: all 16 q, 200-d strip per block; partial top2 -> WS_C2 -------
__global__ __launch_bounds__(256) void kconv(const float* __restrict__ c1w,
                                             const float* __restrict__ c1b,
                                             const float* __restrict__ c2w,
                                             const float* __restrict__ c2b,
                                             const float* __restrict__ c3w,
                                             const float* __restrict__ c3b,
                                             float* __restrict__ ws) {
    int b = blockIdx.y;
    int strip = blockIdx.x;
    int c0 = strip * 200;
    int tid = threadIdx.x;
    __shared__ float S[18][204];   // rows 16,17 zero-padded; 2-col halo
    for (int idx = tid; idx < 18 * 202; idx += 256) {
        int row = idx / 202, col = idx % 202;
        int c = c0 + col;
        float v = 0.f;
        if (row < NQ && c < ND) v = ws[WS_SIM + (size_t)(b * NQ + row) * ND + c];
        S[row][col] = v;
    }
    __syncthreads();
    int q = tid & 15, dg = tid >> 4;   // 16 q x 16 d-groups
    float a1[3] = {-FLT_MAX,-FLT_MAX,-FLT_MAX};
    float a2[3] = {-FLT_MAX,-FLT_MAX,-FLT_MAX};
    for (int j = 0; j < 13; ++j) {
        int dl = dg + j * 16;
        if (dl < 200 && c0 + dl < ND) {
            float s00 = S[q][dl],     s01 = S[q][dl + 1],     s02 = S[q][dl + 2];
            float s10 = S[q + 1][dl], s11 = S[q + 1][dl + 1], s12 = S[q + 1][dl + 2];
            float s20 = S[q + 2][dl], s21 = S[q + 2][dl + 1], s22 = S[q + 2][dl + 2];
            float m1 = -FLT_MAX, m2 = -FLT_MAX, m3 = -FLT_MAX;
            for (int f = 0; f < 32; ++f) {   // uniform scalar weight loads
                float v1 = c1w[f] * s00 + c1b[f];
                m1 = fmaxf(m1, v1);
                float v2 = c2b[f] + c2w[f*4+0]*s00 + c2w[f*4+1]*s01
                                  + c2w[f*4+2]*s10 + c2w[f*4+3]*s11;
                m2 = fmaxf(m2, v2);
                float v3 = c3b[f] + c3w[f*9+0]*s00 + c3w[f*9+1]*s01 + c3w[f*9+2]*s02
                                  + c3w[f*9+3]*s10 + c3w[f*9+4]*s11 + c3w[f*9+5]*s12
                                  + c3w[f*9+6]*s20 + c3w[f*9+7]*s21 + c3w[f*9+8]*s22;
                m3 = fmaxf(m3, v3);
            }
            m1 = fmaxf(m1, 0.f); m2 = fmaxf(m2, 0.f); m3 = fmaxf(m3, 0.f);
            ins2(a1[0], a2[0], m1); ins2(a1[1], a2[1], m2); ins2(a1[2], a2[2], m3);
        }
    }
    // merge the 4 lanes of each q within the wave (lanes q, q+16, q+32, q+48)
#pragma unroll
    for (int m = 16; m <= 32; m <<= 1) {
#pragma unroll
        for (int ng = 0; ng < 3; ++ng) {
            float b1v = __shfl_xor(a1[ng], m), b2v = __shfl_xor(a2[ng], m);
            merge2(a1[ng], a2[ng], b1v, b2v);
        }
    }
    __shared__ float PART[4][16][6];
    int wv = tid >> 6;
    if ((tid & 63) < 16) {
#pragma unroll
        for (int ng = 0; ng < 3; ++ng) {
            PART[wv][q][ng * 2]     = a1[ng];
            PART[wv][q][ng * 2 + 1] = a2[ng];
        }
    }
    __syncthreads();
    if (tid < 16) {
        float* c2p = ws + WS_C2 + ((size_t)(b * NQ + tid) * 3) * 8 + strip * 2;
#pragma unroll
        for (int ng = 0; ng < 3; ++ng) {
            float x1 = PART[0][tid][ng * 2], x2 = PART[0][tid][ng * 2 + 1];
            merge2(x1, x2, PART[1][tid][ng * 2], PART[1][tid][ng * 2 + 1]);
            merge2(x1, x2, PART[2][tid][ng * 2], PART[2][tid][ng * 2 + 1]);
            merge2(x1, x2, PART[3][tid][ng * 2], PART[3][tid][ng * 2 + 1]);
            c2p[ng * 8] = x1; c2p[ng * 8 + 1] = x2;
        }
    }
}

// ------- kmlp: merge conv strips + 208 -> 32 -> 32 -> 1 -------
__global__ __launch_bounds__(64) void kmlp(const float* __restrict__ w1,
                                           const float* __restrict__ b1,
                                           const float* __restrict__ w2,
                                           const float* __restrict__ b2,
                                           const float* __restrict__ w3,
                                           const float* __restrict__ b3,
                                           const float* __restrict__ ws,
                                           float* __restrict__ out) {
    int b = blockIdx.x, l = threadIdx.x;
    __shared__ float sc[208];
    __shared__ float h[32];
    const float* s = ws + WS_SCORES + (size_t)b * 208;
    for (int i = l; i < 208; i += 64)
        if ((i % 13) >= 6) sc[i] = s[i];       // slots 6..12 from WS_SCORES
    if (l < 48) {                               // slots 0..5 from strip merge
        int q = l / 3, ng = l % 3;
        const float* p = ws + WS_C2 + ((size_t)(b * NQ + q) * 3 + ng) * 8;
        float x1 = p[0], x2 = p[1];
        merge2(x1, x2, p[2], p[3]);
        merge2(x1, x2, p[4], p[5]);
        merge2(x1, x2, p[6], p[7]);
        sc[q * 13 + ng * 2] = x1; sc[q * 13 + ng * 2 + 1] = x2;
    }
    __syncthreads();
    int j = l & 31, half = l >> 5;
    float a = 0.f;
    int i0 = half * 104;
    for (int i = 0; i < 104; ++i) a += sc[i0 + i] * w1[(i0 + i) * 32 + j];
    a += __shfl_xor(a, 32);
    a = fmaxf(a + b1[j], 0.f);
    if (half == 0) h[j] = a;
    __syncthreads();
    float r = 0.f;
    if (half == 0) {
        float a2 = 0.f;
        for (int k = 0; k < 32; ++k) a2 += h[k] * w2[k * 32 + j];
        a2 = fmaxf(a2 + b2[j], 0.f);
        r = a2 * w3[j];
    }
#pragma unroll
    for (int m = 1; m <= 32; m <<= 1) r += __shfl_xor(r, m);
    if (l == 0) out[b] = r + b3[0];
}

extern "C" void kernel_launch(void* const* d_in, const int* in_sizes, int n_in,
                              void* d_out, int out_size, void* d_ws, size_t ws_size,
                              hipStream_t stream) {
    (void)in_sizes; (void)n_in; (void)out_size; (void)ws_size;
    const int*   qrls = (const int*)d_in[0];
    const int*   docw = (const int*)d_in[1];
    const float* emb  = (const float*)d_in[2];
    const float* idf  = (const float*)d_in[3];
    const float* c1w  = (const float*)d_in[4];
    const float* c1b  = (const float*)d_in[5];
    const float* c2w  = (const float*)d_in[6];
    const float* c2b  = (const float*)d_in[7];
    const float* c3w  = (const float*)d_in[8];
    const float* c3b  = (const float*)d_in[9];
    const float* w1   = (const float*)d_in[10];
    const float* b1   = (const float*)d_in[11];
    const float* w2   = (const float*)d_in[12];
    const float* b2   = (const float*)d_in[13];
    const float* w3   = (const float*)d_in[14];
    const float* b3   = (const float*)d_in[15];
    float* ws  = (float*)d_ws;
    float* out = (float*)d_out;

    kq<<<dim3(NB), 256, 0, stream>>>(qrls, emb, idf, ws);
    kfused<<<dim3(13, NB), 256, 0, stream>>>(docw, emb, ws);
    kctxtop<<<dim3(4, NB), 256, 0, stream>>>(ws);
    kconv<<<dim3(4, NB), 256, 0, stream>>>(c1w, c1b, c2w, c2b, c3w, c3b, ws);
    kmlp<<<dim3(NB), 64, 0, stream>>>(w1, b1, w2, b2, w3, b3, ws, out);
}

// Round 7
// 170.904 us; speedup vs baseline: 1.0283x; 1.0283x over previous
//
#include <hip/hip_runtime.h>
#include <float.h>
#include <math.h>

#define NB 128
#define NQ 16
#define ND 800
#define NE 300

// workspace layout (float offsets). All regions written every call.
#define WS_SIM    0                          // [NB][NQ][ND] raw dots (= cosine, unit rows)
#define WS_CTXINV (NB*NQ*ND)                 // [NB][ND] 1/(||ctx||/9+1e-9)
#define WS_SCORES (WS_CTXINV + NB*ND)        // [NB][NQ][13] (slots 6..12 used)
#define WS_C2     (WS_SCORES + NB*NQ*13)     // [NB][NQ][3][4 strips][2] partial top2
#define WS_QBF    (WS_C2 + NB*NQ*24)         // [NB][16][320] bf16 (q, zero-padded K)

#define PITCH 344                             // LDS row pitch in bf16 elems (688 B)
#define NIT   6                               // staged 64B items per thread

typedef __attribute__((ext_vector_type(8))) short short8;
typedef __attribute__((ext_vector_type(4))) float f32x4;

__device__ __forceinline__ unsigned short f2bf(float x) {   // RNE fp32->bf16
    unsigned u = __float_as_uint(x);
    u += 0x7FFF + ((u >> 16) & 1);
    return (unsigned short)(u >> 16);
}

__device__ __forceinline__ float bf2f(unsigned short u) {
    return __uint_as_float(((unsigned)u) << 16);
}

__device__ __forceinline__ void ins6(float t[6], float v) {
    if (v > t[5]) t[5] = v;
    float a;
    if (t[5] > t[4]) { a = t[4]; t[4] = t[5]; t[5] = a; }
    if (t[4] > t[3]) { a = t[3]; t[3] = t[4]; t[4] = a; }
    if (t[3] > t[2]) { a = t[2]; t[2] = t[3]; t[3] = a; }
    if (t[2] > t[1]) { a = t[1]; t[1] = t[2]; t[2] = a; }
    if (t[1] > t[0]) { a = t[0]; t[0] = t[1]; t[1] = a; }
}

__device__ __forceinline__ void ins2(float& a1, float& a2, float v) {
    if (v > a2) a2 = v;
    if (a2 > a1) { float t = a1; a1 = a2; a2 = t; }
}

__device__ __forceinline__ void merge2(float& a1, float& a2, float b1v, float b2v) {
    float hi = fmaxf(a1, b1v), lo = fminf(a1, b1v);
    a1 = hi;
    a2 = fmaxf(lo, fmaxf(a2, b2v));
}

// sliding sum of 8 consecutive lanes (this lane .. lane+7)
__device__ __forceinline__ float slide8(float s) {
    s += __shfl_down(s, 1);
    s += __shfl_down(s, 2);
    s += __shfl_down(s, 4);
    return s;
}

// ------- kq: q -> bf16 [16][320] (zero-padded) + idf -------
__global__ __launch_bounds__(256) void kq(const int* __restrict__ qrls,
                                          const float* __restrict__ emb,
                                          const float* __restrict__ idf,
                                          float* __restrict__ ws) {
    int b = blockIdx.x;
    int tid = threadIdx.x;
    unsigned short* qbf = (unsigned short*)(ws + WS_QBF) + (size_t)b * 16 * 320;
    for (int idx = tid; idx < 16 * 160; idx += 256) {
        int q = idx / 160, pr = idx % 160;
        int row = qrls[b * NQ + q];
        int e = pr * 2;
        float x0 = (e < NE) ? emb[(size_t)row * NE + e] : 0.f;
        float x1 = (e + 1 < NE) ? emb[(size_t)row * NE + e + 1] : 0.f;
        unsigned pack = (unsigned)f2bf(x0) | ((unsigned)f2bf(x1) << 16);
        *(unsigned*)(qbf + q * 320 + e) = pack;
    }
    if (tid < NQ) {
        int row = qrls[b * NQ + tid];
        ws[WS_SCORES + (b * NQ + tid) * 13 + 12] = idf[row];
    }
}

// ------- kfused: grid (13, NB), 256 thr = 4 waves -------
// Staging rewritten for MLP: 72 rows x 19 seg64 (64B) = 1368 items, 6/thread.
// Batch: (A) 6 docw index loads, (B) 24 independent float4 loads in flight,
// (C) convert + 2x ds_write_b128. Then MFMA sim (B-frags from LDS) + ctx-norm.
__global__ __launch_bounds__(256, 2) void kfused(const int* __restrict__ docw,
                                                 const float* __restrict__ emb,
                                                 float* __restrict__ ws) {
    int b = blockIdx.y;
    int base = blockIdx.x * 64;
    int tid = threadIdx.x;
    __shared__ unsigned short slds[72 * PITCH];   // 49.5 KB

    // ---- phase A: item decode + docw index batch-load ----
    int ridx[NIT], ro[NIT], so[NIT];
    bool ok[NIT], wr[NIT];
#pragma unroll
    for (int i = 0; i < NIT; ++i) {
        int item = i * 256 + tid;
        int r = item / 19;
        int seg = item - r * 19;
        wr[i] = (item < 1368);
        int rg = base - 4 + r;
        ok[i] = wr[i] && (rg >= 0) && (rg < ND);
        ro[i] = r; so[i] = seg;
        ridx[i] = ok[i] ? docw[b * ND + rg] : 0;
    }
    // ---- phase B: 24 independent float4 loads ----
    float4 d0[NIT], d1[NIT], d2[NIT], d3[NIT];
    float4 z4 = {0.f, 0.f, 0.f, 0.f};
#pragma unroll
    for (int i = 0; i < NIT; ++i) {
        const float* p = emb + (size_t)ridx[i] * NE + so[i] * 16;
        d0[i] = ok[i] ? *(const float4*)(p)      : z4;
        d1[i] = ok[i] ? *(const float4*)(p + 4)  : z4;
        d2[i] = ok[i] ? *(const float4*)(p + 8)  : z4;
        d3[i] = (ok[i] && so[i] < 18) ? *(const float4*)(p + 12) : z4;  // row tail
    }
    // ---- phase C: convert + LDS write ----
#pragma unroll
    for (int i = 0; i < NIT; ++i) {
        if (wr[i]) {
            short8 v0, v1;
            v0[0] = (short)f2bf(d0[i].x); v0[1] = (short)f2bf(d0[i].y);
            v0[2] = (short)f2bf(d0[i].z); v0[3] = (short)f2bf(d0[i].w);
            v0[4] = (short)f2bf(d1[i].x); v0[5] = (short)f2bf(d1[i].y);
            v0[6] = (short)f2bf(d1[i].z); v0[7] = (short)f2bf(d1[i].w);
            v1[0] = (short)f2bf(d2[i].x); v1[1] = (short)f2bf(d2[i].y);
            v1[2] = (short)f2bf(d2[i].z); v1[3] = (short)f2bf(d2[i].w);
            v1[4] = (short)f2bf(d3[i].x); v1[5] = (short)f2bf(d3[i].y);
            v1[6] = (short)f2bf(d3[i].z); v1[7] = (short)f2bf(d3[i].w);
            unsigned short* w = &slds[ro[i] * PITCH + so[i] * 16];
            *(short8*)(w)     = v0;
            *(short8*)(w + 8) = v1;
        }
    }
    // K-pad elems 304..319 of each row -> zero (MFMA reads through 320)
    if (tid < 72) {
        short8 z8 = {0, 0, 0, 0, 0, 0, 0, 0};
        *(short8*)&slds[tid * PITCH + 304] = z8;
        *(short8*)&slds[tid * PITCH + 312] = z8;
    }
    __syncthreads();

    int wv = tid >> 6, lane = tid & 63;
    int rsub = lane & 15, kgrp = lane >> 4;

    // ---- MFMA sim tile: cols base+16*wv .. +16, all 16 q, K=320 ----
    const unsigned short* qb = (const unsigned short*)(ws + WS_QBF)
                               + ((size_t)b * 16 + rsub) * 320 + kgrp * 8;
    f32x4 acc = {0.f, 0.f, 0.f, 0.f};
    const unsigned short* bp = &slds[(16 * wv + rsub + 4) * PITCH + kgrp * 8];
#pragma unroll
    for (int k = 0; k < 10; ++k) {
        short8 af = *(const short8*)(qb + k * 32);
        short8 bf = *(const short8*)(bp + k * 32);
        acc = __builtin_amdgcn_mfma_f32_16x16x32_bf16(af, bf, acc, 0, 0, 0);
    }
    int col = base + 16 * wv + rsub;
    if (col < ND) {
        float* simp = ws + WS_SIM + (size_t)b * NQ * ND + col;
#pragma unroll
        for (int i = 0; i < 4; ++i)
            simp[(size_t)(kgrp * 4 + i) * ND] = acc[i];
    }

    // ---- ctx-norm: waves 0,1; lane l holds staged row 32*wv + l (l<40) ----
    if (wv < 2) {
        int rl = 32 * wv + lane;
        float sq = 0.f;
        for (int seg = 0; seg < 38; ++seg) {
            float xs[8];
            if (lane < 40) {
                short8 x = *(const short8*)&slds[rl * PITCH + seg * 8];
#pragma unroll
                for (int e = 0; e < 8; ++e) xs[e] = bf2f((unsigned short)x[e]);
            } else {
#pragma unroll
                for (int e = 0; e < 8; ++e) xs[e] = 0.f;
            }
#pragma unroll
            for (int e = 0; e < 8; ++e) {
                float s = slide8(xs[e]);
                sq = fmaf(s, s, sq);
            }
        }
        int d = base + 32 * wv + lane;
        if (lane < 32 && d < ND)
            ws[WS_CTXINV + b * ND + d] = 1.f / (sqrtf(sq) * (1.f / 9.f) + 1e-9f);
    }
}

// ------- kctxtop: prefix scan of raw dots -> context cosine -> top-6 -------
__global__ __launch_bounds__(256) void kctxtop(float* __restrict__ ws) {
    int b = blockIdx.y;
    int w = threadIdx.x >> 6, lane = threadIdx.x & 63;
    int q = blockIdx.x * 4 + w;
    __shared__ float P[4][ND];
    const float* simrow = ws + WS_SIM + (size_t)(b * NQ + q) * ND;
    const float* cinv = ws + WS_CTXINV + b * ND;
    float carry = 0.f;
    for (int c = 0; c < 13; ++c) {
        int d = c * 64 + lane;
        float v = (d < ND) ? simrow[d] : 0.f;
#pragma unroll
        for (int off = 1; off < 64; off <<= 1) {
            float t = __shfl_up(v, off);
            if (lane >= off) v += t;
        }
        v += carry;
        if (d < ND) P[w][d] = v;
        carry = __shfl(v, 63);
    }
    __syncthreads();
    float top[6] = {-FLT_MAX,-FLT_MAX,-FLT_MAX,-FLT_MAX,-FLT_MAX,-FLT_MAX};
    for (int c = 0; c < 13; ++c) {
        int d = c * 64 + lane;
        if (d < ND) {
            int hi_i = (d + 3 < ND) ? d + 3 : ND - 1;
            float hi = P[w][hi_i];
            float lo = (d >= 5) ? P[w][d - 5] : 0.f;
            float ctx = (hi - lo) * (1.f / 9.f) * cinv[d];
            ins6(top, ctx);
        }
    }
#pragma unroll
    for (int m = 1; m < 64; m <<= 1) {
        float o0 = __shfl_xor(top[0], m), o1 = __shfl_xor(top[1], m);
        float o2 = __shfl_xor(top[2], m), o3 = __shfl_xor(top[3], m);
        float o4 = __shfl_xor(top[4], m), o5 = __shfl_xor(top[5], m);
        ins6(top, o0); ins6(top, o1); ins6(top, o2);
        ins6(top, o3); ins6(top, o4); ins6(top, o5);
    }
    if (lane == 0) {
        float* sc = ws + WS_SCORES + (size_t)(b * NQ + q) * 13;
        sc[6] = top[0]; sc[7] = top[1]; sc[8]  = top[2];
        sc[9] = top[3]; sc[10] = top[4]; sc[11] = top[5];
    }
}

// ------- kconv: all 16 q, 200-d strip per block; partial top2 -> WS_C2 -------
__global__ __launch_bounds__(256) void kconv(const float* __restrict__ c1w,
                                             const float* __restrict__ c1b,
                                             const float* __restrict__ c2w,
                                             const float* __restrict__ c2b,
                                             const float* __restrict__ c3w,
                                             const float* __restrict__ c3b,
                                             float* __restrict__ ws) {
    int b = blockIdx.y;
    int strip = blockIdx.x;
    int c0 = strip * 200;
    int tid = threadIdx.x;
    __shared__ float S[18][204];   // rows 16,17 zero-padded; 2-col halo
    for (int idx = tid; idx < 18 * 202; idx += 256) {
        int row = idx / 202, col = idx % 202;
        int c = c0 + col;
        float v = 0.f;
        if (row < NQ && c < ND) v = ws[WS_SIM + (size_t)(b * NQ + row) * ND + c];
        S[row][col] = v;
    }
    __syncthreads();
    int q = tid & 15, dg = tid >> 4;   // 16 q x 16 d-groups
    float a1[3] = {-FLT_MAX,-FLT_MAX,-FLT_MAX};
    float a2[3] = {-FLT_MAX,-FLT_MAX,-FLT_MAX};
    for (int j = 0; j < 13; ++j) {
        int dl = dg + j * 16;
        if (dl < 200 && c0 + dl < ND) {
            float s00 = S[q][dl],     s01 = S[q][dl + 1],     s02 = S[q][dl + 2];
            float s10 = S[q + 1][dl], s11 = S[q + 1][dl + 1], s12 = S[q + 1][dl + 2];
            float s20 = S[q + 2][dl], s21 = S[q + 2][dl + 1], s22 = S[q + 2][dl + 2];
            float m1 = -FLT_MAX, m2 = -FLT_MAX, m3 = -FLT_MAX;
            for (int f = 0; f < 32; ++f) {   // uniform scalar weight loads
                float v1 = c1w[f] * s00 + c1b[f];
                m1 = fmaxf(m1, v1);
                float v2 = c2b[f] + c2w[f*4+0]*s00 + c2w[f*4+1]*s01
                                  + c2w[f*4+2]*s10 + c2w[f*4+3]*s11;
                m2 = fmaxf(m2, v2);
                float v3 = c3b[f] + c3w[f*9+0]*s00 + c3w[f*9+1]*s01 + c3w[f*9+2]*s02
                                  + c3w[f*9+3]*s10 + c3w[f*9+4]*s11 + c3w[f*9+5]*s12
                                  + c3w[f*9+6]*s20 + c3w[f*9+7]*s21 + c3w[f*9+8]*s22;
                m3 = fmaxf(m3, v3);
            }
            m1 = fmaxf(m1, 0.f); m2 = fmaxf(m2, 0.f); m3 = fmaxf(m3, 0.f);
            ins2(a1[0], a2[0], m1); ins2(a1[1], a2[1], m2); ins2(a1[2], a2[2], m3);
        }
    }
    // merge the 4 lanes of each q within the wave (lanes q, q+16, q+32, q+48)
#pragma unroll
    for (int m = 16; m <= 32; m <<= 1) {
#pragma unroll
        for (int ng = 0; ng < 3; ++ng) {
            float b1v = __shfl_xor(a1[ng], m), b2v = __shfl_xor(a2[ng], m);
            merge2(a1[ng], a2[ng], b1v, b2v);
        }
    }
    __shared__ float PART[4][16][6];
    int wv = tid >> 6;
    if ((tid & 63) < 16) {
#pragma unroll
        for (int ng = 0; ng < 3; ++ng) {
            PART[wv][q][ng * 2]     = a1[ng];
            PART[wv][q][ng * 2 + 1] = a2[ng];
        }
    }
    __syncthreads();
    if (tid < 16) {
        float* c2p = ws + WS_C2 + ((size_t)(b * NQ + tid) * 3) * 8 + strip * 2;
#pragma unroll
        for (int ng = 0; ng < 3; ++ng) {
            float x1 = PART[0][tid][ng * 2], x2 = PART[0][tid][ng * 2 + 1];
            merge2(x1, x2, PART[1][tid][ng * 2], PART[1][tid][ng * 2 + 1]);
            merge2(x1, x2, PART[2][tid][ng * 2], PART[2][tid][ng * 2 + 1]);
            merge2(x1, x2, PART[3][tid][ng * 2], PART[3][tid][ng * 2 + 1]);
            c2p[ng * 8] = x1; c2p[ng * 8 + 1] = x2;
        }
    }
}

// ------- kmlp: merge conv strips + 208 -> 32 -> 32 -> 1 -------
__global__ __launch_bounds__(64) void kmlp(const float* __restrict__ w1,
                                           const float* __restrict__ b1,
                                           const float* __restrict__ w2,
                                           const float* __restrict__ b2,
                                           const float* __restrict__ w3,
                                           const float* __restrict__ b3,
                                           const float* __restrict__ ws,
                                           float* __restrict__ out) {
    int b = blockIdx.x, l = threadIdx.x;
    __shared__ float sc[208];
    __shared__ float h[32];
    const float* s = ws + WS_SCORES + (size_t)b * 208;
    for (int i = l; i < 208; i += 64)
        if ((i % 13) >= 6) sc[i] = s[i];       // slots 6..12 from WS_SCORES
    if (l < 48) {                               // slots 0..5 from strip merge
        int q = l / 3, ng = l % 3;
        const float* p = ws + WS_C2 + ((size_t)(b * NQ + q) * 3 + ng) * 8;
        float x1 = p[0], x2 = p[1];
        merge2(x1, x2, p[2], p[3]);
        merge2(x1, x2, p[4], p[5]);
        merge2(x1, x2, p[6], p[7]);
        sc[q * 13 + ng * 2] = x1; sc[q * 13 + ng * 2 + 1] = x2;
    }
    __syncthreads();
    int j = l & 31, half = l >> 5;
    float a = 0.f;
    int i0 = half * 104;
    for (int i = 0; i < 104; ++i) a += sc[i0 + i] * w1[(i0 + i) * 32 + j];
    a += __shfl_xor(a, 32);
    a = fmaxf(a + b1[j], 0.f);
    if (half == 0) h[j] = a;
    __syncthreads();
    float r = 0.f;
    if (half == 0) {
        float a2 = 0.f;
        for (int k = 0; k < 32; ++k) a2 += h[k] * w2[k * 32 + j];
        a2 = fmaxf(a2 + b2[j], 0.f);
        r = a2 * w3[j];
    }
#pragma unroll
    for (int m = 1; m <= 32; m <<= 1) r += __shfl_xor(r, m);
    if (l == 0) out[b] = r + b3[0];
}

extern "C" void kernel_launch(void* const* d_in, const int* in_sizes, int n_in,
                              void* d_out, int out_size, void* d_ws, size_t ws_size,
                              hipStream_t stream) {
    (void)in_sizes; (void)n_in; (void)out_size; (void)ws_size;
    const int*   qrls = (const int*)d_in[0];
    const int*   docw = (const int*)d_in[1];
    const float* emb  = (const float*)d_in[2];
    const float* idf  = (const float*)d_in[3];
    const float* c1w  = (const float*)d_in[4];
    const float* c1b  = (const float*)d_in[5];
    const float* c2w  = (const float*)d_in[6];
    const float* c2b  = (const float*)d_in[7];
    const float* c3w  = (const float*)d_in[8];
    const float* c3b  = (const float*)d_in[9];
    const float* w1   = (const float*)d_in[10];
    const float* b1   = (const float*)d_in[11];
    const float* w2   = (const float*)d_in[12];
    const float* b2   = (const float*)d_in[13];
    const float* w3   = (const float*)d_in[14];
    const float* b3   = (const float*)d_in[15];
    float* ws  = (float*)d_ws;
    float* out = (float*)d_out;

    kq<<<dim3(NB), 256, 0, stream>>>(qrls, emb, idf, ws);
    kfused<<<dim3(13, NB), 256, 0, stream>>>(docw, emb, ws);
    kctxtop<<<dim3(4, NB), 256, 0, stream>>>(ws);
    kconv<<<dim3(4, NB), 256, 0, stream>>>(c1w, c1b, c2w, c2b, c3w, c3b, ws);
    kmlp<<<dim3(NB), 64, 0, stream>>>(w1, b1, w2, b2, w3, b3, ws, out);
}